// Round 10
// baseline (402.896 us; speedup 1.0000x reference)
//
#include <hip/hip_runtime.h>
#include <hip/hip_bf16.h>

#define S_LEN 2048
#define DIM   1024
#define NHEAD 16
#define HDIM  64
#define QSCALE 0.18033688f   // log2(e)/8, folded into Q at projection time

typedef __attribute__((ext_vector_type(8))) short bfrag;   // 8 bf16 = 4 VGPRs
typedef __attribute__((ext_vector_type(4))) float f32x4;   // MFMA C/D 16x16
typedef __attribute__((ext_vector_type(16))) float f32x16; // MFMA C/D 32x32
typedef __attribute__((ext_vector_type(4))) unsigned int u32x4;

#define MFMA(a,b,c)   __builtin_amdgcn_mfma_f32_16x16x32_bf16((a),(b),(c),0,0,0)
#define MFMA32(a,b,c) __builtin_amdgcn_mfma_f32_32x32x16_bf16((a),(b),(c),0,0,0)

__device__ __forceinline__ unsigned short f2bf(float x) {
  __hip_bfloat16 h = __float2bfloat16(x);
  return *reinterpret_cast<unsigned short*>(&h);
}

// packed 2xf32 -> 2xbf16 (v_cvt_pk_bf16_f32 on gfx950)
__device__ __forceinline__ unsigned int pk2bf(float a, float b) {
  float2 f2; f2.x = a; f2.y = b;
  __hip_bfloat162 b2 = __float22bfloat162_rn(f2);
  return *reinterpret_cast<unsigned int*>(&b2);
}

// async global->LDS, 16B per lane; LDS dest = wave-uniform base + lane*16
__device__ __forceinline__ void gll16(const unsigned short* g, unsigned short* l) {
  __builtin_amdgcn_global_load_lds(
      (const __attribute__((address_space(1))) unsigned int*)g,
      (__attribute__((address_space(3))) unsigned int*)l, 16, 0, 0);
}

// flags[0]: 0 = inputs bf16, 1 = inputs fp32
// flags[1]: mask mode 0=u8, 1=i32, 2=f32, 3=bf16
__global__ void probe(const unsigned int* __restrict__ x,
                      const unsigned int* __restrict__ mask,
                      int* __restrict__ flags) {
  const int lane = threadIdx.x;
  int insane = 0;
  for (int i = lane; i < 512; i += 64) {
    unsigned int w = x[i];
    unsigned int e = (w >> 7) & 0xFFu;
    bool sane = (e >= 90u && e <= 160u) || ((w & 0x7FFFu) == 0u);
    insane += sane ? 0 : 1;
  }
  bool all01 = true, allu8 = true, allf32 = true, allbf = true;
  for (int i = lane; i < 1024; i += 64) {
    unsigned int w = mask[i];
    all01  &= (w <= 1u);
    allu8  &= ((w & 0xFEFEFEFEu) == 0u);
    allf32 &= (w == 0u || w == 0x3F800000u);
    unsigned int lo = w & 0xFFFFu, hi = w >> 16;
    allbf  &= (lo == 0u || lo == 0x3F80u) && (hi == 0u || hi == 0x3F80u);
  }
#pragma unroll
  for (int off = 1; off < 64; off <<= 1) insane += __shfl_xor(insane, off, 64);
  const unsigned long long full = ~0ull;
  const bool g01  = __ballot(all01)  == full;
  const bool gu8  = __ballot(allu8)  == full;
  const bool gf32 = __ballot(allf32) == full;
  const bool gbf  = __ballot(allbf)  == full;
  if (lane == 0) {
    flags[0] = (insane > 128) ? 1 : 0;
    flags[1] = g01 ? 1 : (gu8 ? 0 : (gf32 ? 2 : (gbf ? 3 : 0)));
  }
}

__device__ __forceinline__ bool mask_at(const void* mk, int mode, size_t idx) {
  switch (mode) {
    case 0:  return ((const unsigned char*)mk)[idx]  != 0;
    case 1:  return ((const int*)mk)[idx]            != 0;
    case 2:  return ((const unsigned int*)mk)[idx]   != 0u;
    default: return ((const unsigned short*)mk)[idx] != 0;
  }
}

// One fused conversion kernel: x (4096 blocks) + 4 weights (512 blocks each).
__global__ __launch_bounds__(256) void cvt_all(
    const void* __restrict__ x,  const void* __restrict__ wq,
    const void* __restrict__ wk, const void* __restrict__ wv,
    const void* __restrict__ wo,
    unsigned short* __restrict__ xb,  unsigned short* __restrict__ wqb,
    unsigned short* __restrict__ wkb, unsigned short* __restrict__ wvb,
    unsigned short* __restrict__ wob, const int* __restrict__ flags) {
  const int bx = blockIdx.x;
  const void* src; unsigned short* dst; int i;
  if (bx < 4096) { src = x; dst = xb; i = bx * 256 + threadIdx.x; }
  else {
    const int r = (bx - 4096) >> 9, off = (bx - 4096) & 511;
    src = r == 0 ? wq : r == 1 ? wk : r == 2 ? wv : wo;
    dst = r == 0 ? wqb : r == 1 ? wkb : r == 2 ? wvb : wob;
    i = off * 256 + threadIdx.x;
  }
  if (flags[0]) {
    const float* p = (const float*)src + (size_t)i * 8;
    float4 a = *reinterpret_cast<const float4*>(p);
    float4 b = *reinterpret_cast<const float4*>(p + 4);
    unsigned int d0 = pk2bf(a.x, a.y), d1 = pk2bf(a.z, a.w);
    unsigned int d2 = pk2bf(b.x, b.y), d3 = pk2bf(b.z, b.w);
    uint4 o; o.x = d0; o.y = d1; o.z = d2; o.w = d3;
    *reinterpret_cast<uint4*>(dst + (size_t)i * 8) = o;
  } else {
    *reinterpret_cast<bfrag*>(dst + (size_t)i * 8) =
        reinterpret_cast<const bfrag*>(src)[i];
  }
}

// Bit-pack mask (any mode) -> u64 per 64 keys via ballot.
// TRANSPOSED layout: mb[(b*32 + word) * 2048 + q].
// v14: grid-stride x8 (8192 blocks instead of 65536) to cut scheduling overhead.
__global__ __launch_bounds__(256) void bitmask(const void* __restrict__ mk,
                                               const int* __restrict__ flags,
                                               unsigned long long* __restrict__ mb) {
  const int mode = flags[1];
  const size_t base = (size_t)blockIdx.x * 256 + threadIdx.x;
#pragma unroll
  for (int it = 0; it < 8; ++it) {
    const size_t gid = base + (size_t)it * 2097152;   // 8192*256 stride
    bool v = mask_at(mk, mode, gid);
    unsigned long long w = __ballot(v);
    if ((threadIdx.x & 63) == 0) {
      const size_t bb = gid >> 22;            // S*S = 2^22 per batch
      const size_t q  = (gid >> 11) & 2047;
      const size_t wd = (gid >> 6) & 31;
      mb[(bb * 32 + wd) * 2048 + q] = w;
    }
  }
}

// ---------------- GEMM v3: C(8192xN) = A @ Bt^T, bf16, K=1024, BK=64 ----------------
// BK=64 + XOR-swizzled staging/reads (rule 21) + bijective XCD swizzle (proven).
// cMode=3 region 2 (V) writes DIRECTLY in transposed [bh][64][s] layout.
// cMode: 1 head-split bf16, 2 plain dtype-per-flag, 3 fused-QKV head-split
// (region 0 == Q pre-scaled by QSCALE; region 2 == V transposed).
__global__ __launch_bounds__(256) void gemm128(const unsigned short* __restrict__ A,
                                               const unsigned short* __restrict__ Bt,
                                               void* __restrict__ C,
                                               const int* __restrict__ flags,
                                               int aHsplit, int cMode) {
  __shared__ unsigned short As[128 * 64];
  __shared__ unsigned short Bs[128 * 64];
  const int t = threadIdx.x, lane = t & 63, wave = t >> 6;
  const int r16 = lane & 15, quad = lane >> 4;

  // XCD-aware bijective block swizzle (both grids have nwg % 8 == 0)
  const int nwgx = gridDim.x;
  const int nwg  = nwgx * gridDim.y;
  const int orig = blockIdx.y * nwgx + blockIdx.x;
  const int cpx  = nwg >> 3;
  const int swz  = (orig & 7) * cpx + (orig >> 3);
  const int n0 = (swz % nwgx) * 128, m0 = (swz / nwgx) * 128;

  const int wm = (wave >> 1) * 64, wn = (wave & 1) * 64;
  const int srow = t >> 3;                 // 0..31 rows per staging round
  const int sgr  = (t & 7) ^ (srow & 7);   // inverse-swizzled source granule

  f32x4 acc[4][4];
#pragma unroll
  for (int i = 0; i < 4; ++i)
#pragma unroll
    for (int j = 0; j < 4; ++j) acc[i][j] = (f32x4){0.f, 0.f, 0.f, 0.f};

  for (int k0 = 0; k0 < 1024; k0 += 64) {
    __syncthreads();
#pragma unroll
    for (int rr = 0; rr < 4; ++rr) {
      const int row = rr * 32 + srow;
      const int m = m0 + row;
      const int k = k0 + sgr * 8;
      const unsigned short* ga;
      if (aHsplit) ga = A + ((size_t)(((m >> 11) << 4) + (k >> 6)) * 2048 + (m & 2047)) * 64 + (k & 63);
      else         ga = A + (size_t)m * 1024 + k;
      gll16(ga, As + rr * 2048 + wave * 512);
      const unsigned short* gb = Bt + (size_t)(n0 + row) * 1024 + k;
      gll16(gb, Bs + rr * 2048 + wave * 512);
    }
    __syncthreads();

#pragma unroll
    for (int kk = 0; kk < 2; ++kk) {
      bfrag af[4], bf[4];
#pragma unroll
      for (int i = 0; i < 4; ++i)
        af[i] = *reinterpret_cast<const bfrag*>(
            &As[(wm + i * 16 + r16) * 64 + (((kk * 4 + quad) ^ (r16 & 7)) * 8)]);
#pragma unroll
      for (int j = 0; j < 4; ++j)
        bf[j] = *reinterpret_cast<const bfrag*>(
            &Bs[(wn + j * 16 + r16) * 64 + (((kk * 4 + quad) ^ (r16 & 7)) * 8)]);
#pragma unroll
      for (int i = 0; i < 4; ++i)
#pragma unroll
        for (int j = 0; j < 4; ++j)
          acc[i][j] = MFMA(af[i], bf[j], acc[i][j]);
    }
  }

  const int oF = (cMode == 2) ? flags[0] : 0;
#pragma unroll
  for (int i = 0; i < 4; ++i)
#pragma unroll
    for (int j = 0; j < 4; ++j) {
      const int mb = m0 + wm + i * 16 + quad * 4;   // r=0 token
      const int n  = n0 + wn + j * 16 + r16;
      if (cMode == 3 && (n >> 10) == 2) {
        // V: write transposed [bh][d][s]; 4 consecutive tokens -> one 8B store
        const int nn = n & 1023;
        const int bh = (mb >> 11) * NHEAD + (nn >> 6);
        const size_t idx = (size_t)2 * 8388608 +
            ((size_t)bh * 64 + (nn & 63)) * 2048 + (mb & 2047);
        ushort4 o;
        o.x = f2bf(acc[i][j][0]); o.y = f2bf(acc[i][j][1]);
        o.z = f2bf(acc[i][j][2]); o.w = f2bf(acc[i][j][3]);
        *reinterpret_cast<ushort4*>((unsigned short*)C + idx) = o;
      } else {
#pragma unroll
        for (int r = 0; r < 4; ++r) {
          const int m = mb + r;
          const float v = acc[i][j][r];
          if (cMode == 3) {
            const int region = n >> 10, nn = n & 1023;
            const float vv = (region == 0) ? v * QSCALE : v;
            const size_t idx = (size_t)region * 8388608 +
                ((size_t)((m >> 11) * NHEAD + (nn >> 6)) * 2048 + (m & 2047)) * 64 + (nn & 63);
            ((unsigned short*)C)[idx] = f2bf(vv);
          } else if (cMode == 1) {
            const size_t idx = ((size_t)((m >> 11) * NHEAD + (n >> 6)) * 2048 + (m & 2047)) * 64 + (n & 63);
            ((unsigned short*)C)[idx] = f2bf(v);
          } else {
            const size_t idx = (size_t)m * 1024 + n;
            if (oF) ((float*)C)[idx] = v;
            else    ((unsigned short*)C)[idx] = f2bf(v);
          }
        }
      }
    }
}

// ---------------- fattn v14: v13 math, 2-wave blocks (QBLK=64) ------------------
// Same per-wave math/layout as v13 (passing, ~120us). Block = 128 threads
// (2 waves), grid 2048: barrier groups shrink 4->2 waves (less convoy skew)
// and LDS 32KB/block allows ~5 resident blocks/CU (vs 2-3 of 4) -> finer
// inter-block overlap of the intra-iter serial chain. Staging rows re-split
// across 2 waves; the XOR-swizzle invariant LDS[row][g]=global[row][g^(row&7)]
// is unchanged. Spill tripwire: WRITE_SIZE must stay ~16MB.
#if defined(__has_builtin)
#if __has_builtin(__builtin_amdgcn_permlane32_swap)
#define HAVE_PL32_SWAP 1
#endif
#endif
#ifndef HAVE_PL32_SWAP
#define HAVE_PL32_SWAP 0
#endif

__global__ __launch_bounds__(128, 3) void fattn(const unsigned short* __restrict__ qH,
                                                const unsigned short* __restrict__ kH,
                                                const unsigned short* __restrict__ vT,
                                                const unsigned long long* __restrict__ mbT,
                                                unsigned short* __restrict__ oH) {
  __shared__ unsigned short Ks[2][64 * 64];
  __shared__ unsigned short Vs[2][64 * 64];
  const int t = threadIdx.x, lane = t & 63, wave = t >> 6;   // wave in [0,2)
  const int l31 = lane & 31, hi = lane >> 5;
  const int bid = blockIdx.x;
  const int bh = bid & 63, qidx = bid >> 6;                  // qidx in [0,32)
  const int b = bh >> 4;
  const int qw = qidx * 64 + wave * 32;
  const size_t hbase = (size_t)bh * S_LEN;
  const int kgr = l31 & 7;  // row&7 for both K-frag and V-frag LDS reads

  // Q fragments (B-operand of QK^T): lane holds Q[qw+l31][d = 16s + 8hi + j]
  bfrag qf[4];
#pragma unroll
  for (int s = 0; s < 4; ++s)
    qf[s] = *reinterpret_cast<const bfrag*>(
        qH + (hbase + qw + l31) * 64 + s * 16 + hi * 8);

  f32x16 o0, o1;   // O[q][d] d-halves: row q = (r&3)+8*(r>>2)+4*hi, col d = l31(+32)
#pragma unroll
  for (int r = 0; r < 16; ++r) { o0[r] = 0.f; o1[r] = 0.f; }
  float ls[4] = {0.f, 0.f, 0.f, 0.f};   // 4 partials: break serial fadd chain

  const int srow = lane >> 3;          // 0..7
  const int sg   = (lane & 7) ^ srow;  // inverse-swizzled source granule

  // 2 waves fill K[64][64] + V[64][64]: per rr, wave w stages rows rr*16+w*8+srow
  auto stage = [&](int buf, int kb) {
#pragma unroll
    for (int rr = 0; rr < 4; ++rr) {
      const int row = rr * 16 + wave * 8 + srow;
      gll16(kH + (hbase + kb + row) * 64 + sg * 8, &Ks[buf][rr * 1024 + wave * 512]);
      gll16(vT + ((size_t)bh * 64 + row) * 2048 + kb + sg * 8, &Vs[buf][rr * 1024 + wave * 512]);
    }
  };

  stage(0, 0);
  int cur = 0;
  // transposed mask: mbT[(b*32 + word)*2048 + q]; this lane's q-column base:
  const unsigned long long* mcol = mbT + (size_t)b * 32 * S_LEN + (qw + l31);
  unsigned long long wcur = mcol[0];   // prefetch distance 1

  // softmax + pack + in-reg transpose + PV for one 32-key c-tile
  auto smpv = [&](const f32x16& z, unsigned int wm, int c) {
#pragma unroll
    for (int s2 = 0; s2 < 2; ++s2) {
      float e[8];
#pragma unroll
      for (int j = 0; j < 8; ++j) {
        const int r = 8 * s2 + j;
        const int bitp = (r & 3) + 8 * (r >> 2);
        float ev = __builtin_amdgcn_exp2f(z[r]);
        ev = (wm & (1u << bitp)) ? ev : 0.f;
        e[j] = ev;
        ls[r & 3] += ev;
      }
      const unsigned int pwa = pk2bf(e[0], e[1]);   // keys 16s2+4hi+{0,1}
      const unsigned int pwb = pk2bf(e[2], e[3]);   // keys 16s2+4hi+{2,3}
      const unsigned int pwc = pk2bf(e[4], e[5]);   // keys 16s2+8+4hi+{0,1}
      const unsigned int pwd = pk2bf(e[6], e[7]);   // keys 16s2+8+4hi+{2,3}
      u32x4 uu;
#if HAVE_PL32_SWAP
      auto r02 = __builtin_amdgcn_permlane32_swap(pwa, pwc, false, false);
      auto r13 = __builtin_amdgcn_permlane32_swap(pwb, pwd, false, false);
      uu.x = r02[0];   // k = 8hi + {0,1}
      uu.y = r13[0];   // k = 8hi + {2,3}
      uu.z = r02[1];   // k = 8hi + {4,5}
      uu.w = r13[1];   // k = 8hi + {6,7}
#else
      const unsigned int t0 = __shfl_xor(pwa, 32, 64);
      const unsigned int t1 = __shfl_xor(pwb, 32, 64);
      const unsigned int t2 = __shfl_xor(pwc, 32, 64);
      const unsigned int t3 = __shfl_xor(pwd, 32, 64);
      uu.x = hi ? t2 : pwa;   // k = 8hi + {0,1}
      uu.y = hi ? t3 : pwb;   // k = 8hi + {2,3}
      uu.z = hi ? pwc : t0;   // k = 8hi + {4,5}
      uu.w = hi ? pwd : t1;   // k = 8hi + {6,7}
#endif
      const bfrag pf = __builtin_bit_cast(bfrag, uu);
      const int s = 2 * c + s2;  // absolute 16-key slice
      const int gv = (2 * s + hi) ^ kgr;
      bfrag v0 = *reinterpret_cast<const bfrag*>(&Vs[cur][l31 * 64 + gv * 8]);
      bfrag v1 = *reinterpret_cast<const bfrag*>(&Vs[cur][(32 + l31) * 64 + gv * 8]);
      __builtin_amdgcn_s_setprio(1);
      o0 = MFMA32(pf, v0, o0);
      o1 = MFMA32(pf, v1, o1);
      __builtin_amdgcn_s_setprio(0);
    }
  };

  for (int kb = 0; kb < S_LEN; kb += 64) {
    __syncthreads();
    const bool more = (kb + 64 < S_LEN);
    if (more) stage(cur ^ 1, kb + 64);
    const unsigned long long wnext =
        more ? mcol[(size_t)((kb >> 6) + 1) * S_LEN] : 0ull;

    // lane's keys are {32c + 4*hi + (r&3) + 8*(r>>2)}; shift by 4*hi once, then
    // bit (r&3)+8*(r>>2) of the low(c=0)/high(c=1) u32 selects.
    const unsigned int wlo = (unsigned int)(wcur >> (4 * hi));
    const unsigned int whi = (unsigned int)(wcur >> (32 + 4 * hi));

    // ---- QK^T for BOTH c-tiles first: two independent 4-chains ----
    f32x16 z0, z1;
#pragma unroll
    for (int r = 0; r < 16; ++r) { z0[r] = 0.f; z1[r] = 0.f; }
    __builtin_amdgcn_s_setprio(1);
#pragma unroll
    for (int s = 0; s < 4; ++s) {
      const int gr = (2 * s + hi) ^ kgr;
      bfrag kf0 = *reinterpret_cast<const bfrag*>(&Ks[cur][l31 * 64 + gr * 8]);
      bfrag kf1 = *reinterpret_cast<const bfrag*>(&Ks[cur][(32 + l31) * 64 + gr * 8]);
      z0 = MFMA32(kf0, qf[s], z0);
      z1 = MFMA32(kf1, qf[s], z1);
    }
    __builtin_amdgcn_s_setprio(0);

    // ---- softmax+PV c=0, then c=1 (PV(c0) MFMAs overlap softmax(c1) VALU) ----
    smpv(z0, wlo, 0);
    smpv(z1, whi, 1);

    wcur = wnext;
    cur ^= 1;
  }

  // denom: lane-local sum covers this q's keys with bit2==hi; partner has the rest
  float lsum = (ls[0] + ls[1]) + (ls[2] + ls[3]);
  lsum += __shfl_xor(lsum, 32, 64);
  const float inv = 1.f / fmaxf(lsum, 1e-30f);
#pragma unroll
  for (int r = 0; r < 16; ++r) {
    const int qr = (r & 3) + 8 * (r >> 2) + 4 * hi;
    const float sc = __shfl(inv, qr, 64);  // lane qr holds inv for q = qw+qr
    unsigned short* op = oH + (hbase + qw + qr) * 64 + l31;
    op[0]  = f2bf(o0[r] * sc);
    op[32] = f2bf(o1[r] * sc);
  }
}

// ======================= round-2 fallback (small ws) =======================
template<bool F32>
__device__ __forceinline__ bfrag load8(const void* base, size_t idx) {
  if constexpr (F32) {
    const float* p = (const float*)base + idx;
    float4 u = *reinterpret_cast<const float4*>(p);
    float4 v = *reinterpret_cast<const float4*>(p + 4);
    bfrag r;
    r[0]=(short)f2bf(u.x); r[1]=(short)f2bf(u.y); r[2]=(short)f2bf(u.z); r[3]=(short)f2bf(u.w);
    r[4]=(short)f2bf(v.x); r[5]=(short)f2bf(v.y); r[6]=(short)f2bf(v.z); r[7]=(short)f2bf(v.w);
    return r;
  } else {
    return *reinterpret_cast<const bfrag*>((const unsigned short*)base + idx);
  }
}

template<bool AF32, bool BF32>
__device__ __forceinline__ void gemm_body(const void* __restrict__ A, const void* __restrict__ Bt,
                                          void* __restrict__ C, int N, int K, bool outF32) {
  const int lane = threadIdx.x & 63, wave = threadIdx.x >> 6;
  const int r16 = lane & 15, quad = lane >> 4;
  const int m0 = (blockIdx.y * 4 + wave) * 16, n0 = blockIdx.x * 64;
  f32x4 acc[4];
#pragma unroll
  for (int i = 0; i < 4; ++i) acc[i] = (f32x4){0.f,0.f,0.f,0.f};
  const size_t aoff = (size_t)(m0 + r16) * K + quad * 8;
  const size_t boff = (size_t)(n0 + r16) * K + quad * 8;
  for (int k0 = 0; k0 < K; k0 += 32) {
    bfrag a = load8<AF32>(A, aoff + k0);
#pragma unroll
    for (int tt = 0; tt < 4; ++tt) {
      bfrag bb = load8<BF32>(Bt, boff + (size_t)tt * 16 * K + k0);
      acc[tt] = MFMA(a, bb, acc[tt]);
    }
  }
#pragma unroll
  for (int tt = 0; tt < 4; ++tt)
#pragma unroll
    for (int r = 0; r < 4; ++r) {
      const size_t ci = (size_t)(m0 + quad * 4 + r) * N + n0 + tt * 16 + r16;
      if (outF32) ((float*)C)[ci] = acc[tt][r];
      else        ((unsigned short*)C)[ci] = f2bf(acc[tt][r]);
    }
}

__global__ __launch_bounds__(256) void gemm_bt(const void* A, const void* Bt, void* C,
                                               int N, int K, const int* flags,
                                               int aFollows, int outFollows) {
  const int f = flags[0];
  const bool aF = (aFollows != 0) && (f != 0);
  const bool oF = (outFollows != 0) && (f != 0);
  if (f) { if (aF) gemm_body<true, true>(A, Bt, C, N, K, oF);
           else    gemm_body<false, true>(A, Bt, C, N, K, oF); }
  else     gemm_body<false, false>(A, Bt, C, N, K, oF);
}

__global__ __launch_bounds__(64) void fattn_r2(const unsigned short* __restrict__ xq,
                                               const unsigned short* __restrict__ xk,
                                               const unsigned short* __restrict__ xv,
                                               const void* __restrict__ mk,
                                               const int* __restrict__ flags,
                                               unsigned short* __restrict__ xo) {
  __shared__ unsigned short smemP[16 * 32];
  const int lane = threadIdx.x, r16 = lane & 15, quad = lane >> 4;
  const int q0 = blockIdx.x * 16, h = blockIdx.y, b = blockIdx.z;
  const int mmode = flags[1];
  const size_t base = (size_t)b * S_LEN * DIM + (size_t)h * HDIM;
  const size_t mbase = (size_t)b * S_LEN * S_LEN;
  bfrag aq0 = *reinterpret_cast<const bfrag*>(xq + base + (size_t)(q0 + r16) * DIM + quad * 8);
  bfrag aq1 = *reinterpret_cast<const bfrag*>(xq + base + (size_t)(q0 + r16) * DIM + 32 + quad * 8);
  f32x4 o[4];
#pragma unroll
  for (int i = 0; i < 4; ++i) o[i] = (f32x4){0.f,0.f,0.f,0.f};
  float m_r[4] = {-1e30f,-1e30f,-1e30f,-1e30f}, l_r[4] = {0.f,0.f,0.f,0.f};
  for (int kb = 0; kb < S_LEN; kb += 32) {
    const unsigned short* k0p = xk + base + (size_t)(kb + r16) * DIM + quad * 8;
    const unsigned short* k1p = k0p + (size_t)16 * DIM;
    f32x4 s0 = (f32x4){0.f,0.f,0.f,0.f}, s1 = (f32x4){0.f,0.f,0.f,0.f};
    s0 = MFMA(aq0, *reinterpret_cast<const bfrag*>(k0p), s0);
    s0 = MFMA(aq1, *reinterpret_cast<const bfrag*>(k0p + 32), s0);
    s1 = MFMA(aq0, *reinterpret_cast<const bfrag*>(k1p), s1);
    s1 = MFMA(aq1, *reinterpret_cast<const bfrag*>(k1p + 32), s1);
    float l0[4], l1[4], tmax[4];
#pragma unroll
    for (int r = 0; r < 4; ++r) {
      const size_t mrow = mbase + (size_t)(q0 + quad * 4 + r) * S_LEN + kb;
      l0[r] = mask_at(mk, mmode, mrow + r16) ? s0[r] * 0.125f : -1e30f;
      l1[r] = mask_at(mk, mmode, mrow + 16 + r16) ? s1[r] * 0.125f : -1e30f;
      tmax[r] = fmaxf(l0[r], l1[r]);
    }
#pragma unroll
    for (int off = 1; off < 16; off <<= 1)
#pragma unroll
      for (int r = 0; r < 4; ++r) tmax[r] = fmaxf(tmax[r], __shfl_xor(tmax[r], off, 64));
    float p0[4], p1[4], rsum[4];
#pragma unroll
    for (int r = 0; r < 4; ++r) {
      const float mnew = fmaxf(m_r[r], tmax[r]);
      const float alpha = __expf(m_r[r] - mnew);
      m_r[r] = mnew;
      p0[r] = (l0[r] <= -1e29f) ? 0.f : __expf(l0[r] - mnew);
      p1[r] = (l1[r] <= -1e29f) ? 0.f : __expf(l1[r] - mnew);
      rsum[r] = p0[r] + p1[r];
      l_r[r] *= alpha;
#pragma unroll
      for (int tt = 0; tt < 4; ++tt) o[tt][r] *= alpha;
    }
#pragma unroll
    for (int off = 1; off < 16; off <<= 1)
#pragma unroll
      for (int r = 0; r < 4; ++r) rsum[r] += __shfl_xor(rsum[r], off, 64);
#pragma unroll
    for (int r = 0; r < 4; ++r) l_r[r] += rsum[r];
#pragma unroll
    for (int r = 0; r < 4; ++r) {
      smemP[(quad * 4 + r) * 32 + r16] = f2bf(p0[r]);
      smemP[(quad * 4 + r) * 32 + 16 + r16] = f2bf(p1[r]);
    }
    __syncthreads();
    bfrag apf = *reinterpret_cast<const bfrag*>(&smemP[r16 * 32 + quad * 8]);
    const unsigned short* vbase = xv + base + (size_t)(kb + quad * 8) * DIM + r16;
#pragma unroll
    for (int tt = 0; tt < 4; ++tt) {
      bfrag bv;
#pragma unroll
      for (int j = 0; j < 8; ++j) bv[j] = (short)vbase[(size_t)j * DIM + tt * 16];
      o[tt] = MFMA(apf, bv, o[tt]);
    }
    __syncthreads();
  }
#pragma unroll
  for (int tt = 0; tt < 4; ++tt)
#pragma unroll
    for (int r = 0; r < 4; ++r)
      xo[base + (size_t)(q0 + quad * 4 + r) * DIM + tt * 16 + r16] = f2bf(o[tt][r] / l_r[r]);
}

extern "C" void kernel_launch(void* const* d_in, const int* in_sizes, int n_in,
                              void* d_out, int out_size, void* d_ws, size_t ws_size,
                              hipStream_t stream) {
  const void* x  = d_in[0];
  const void* mk = d_in[1];
  const void* wq = d_in[2];
  const void* wk = d_in[3];
  const void* wv = d_in[4];
  const void* wo = d_in[5];

  const size_t MiB = 1048576;
  const size_t NEED = 4096 + 90 * MiB;

  if (ws_size >= NEED) {
    char* p = (char*)d_ws;
    int* flags = (int*)p;                       p += 4096;
    unsigned short* xb  = (unsigned short*)p;   p += 16 * MiB;
    unsigned short* wqb = (unsigned short*)p;   p += 2 * MiB;
    unsigned short* wkb = (unsigned short*)p;   p += 2 * MiB;
    unsigned short* wvb = (unsigned short*)p;   p += 2 * MiB;
    unsigned short* wob = (unsigned short*)p;   p += 2 * MiB;
    unsigned long long* mb = (unsigned long long*)p; p += 2 * MiB;
    unsigned short* xqH = (unsigned short*)p;   p += 16 * MiB;  // xq/xk contiguous,
    unsigned short* xkH = (unsigned short*)p;   p += 16 * MiB;  // then V (transposed)
    unsigned short* xvT = (unsigned short*)p;   p += 16 * MiB;  // region 2 of cMode=3
    unsigned short* xoH = (unsigned short*)p;   p += 16 * MiB;  // attn out (head-split)
    (void)xkH; (void)xvT;

    probe<<<1, 64, 0, stream>>>((const unsigned int*)x, (const unsigned int*)mk, flags);
    cvt_all<<<6144, 256, 0, stream>>>(x, wq, wk, wv, wo, xb, wqb, wkb, wvb, wob, flags);
    bitmask<<<8192, 256, 0, stream>>>(mk, flags, mb);

    gemm128<<<dim3(24, 64), 256, 0, stream>>>(xb, wqb, xqH, flags, 0, 3);
    fattn<<<dim3(2048), 128, 0, stream>>>(xqH, xkH, xvT, mb, xoH);
    gemm128<<<dim3(8, 64), 256, 0, stream>>>(xoH, wob, d_out, flags, 1, 2);
  } else {
    // round-2 fallback
    int* flags = (int*)d_ws;
    unsigned short* xq = (unsigned short*)((char*)d_ws + 256);
    unsigned short* xk = xq + (size_t)8388608;
    unsigned short* xv = xk + (size_t)8388608;
    unsigned short* xo = xv + (size_t)8388608;
    probe<<<1, 64, 0, stream>>>((const unsigned int*)x, (const unsigned int*)mk, flags);
    dim3 gg(16, 128);
    gemm_bt<<<gg, 256, 0, stream>>>(x, wq, xq, 1024, 1024, flags, 1, 0);
    gemm_bt<<<gg, 256, 0, stream>>>(x, wk, xk, 1024, 1024, flags, 1, 0);
    gemm_bt<<<gg, 256, 0, stream>>>(x, wv, xv, 1024, 1024, flags, 1, 0);
    fattn_r2<<<dim3(128, NHEAD, 4), 64, 0, stream>>>(xq, xk, xv, mk, flags, xo);
    gemm_bt<<<gg, 256, 0, stream>>>(xo, wo, d_out, 1024, 1024, flags, 0, 1);
  }
}

// Round 11
// 379.088 us; speedup vs baseline: 1.0628x; 1.0628x over previous
//
#include <hip/hip_runtime.h>
#include <hip/hip_bf16.h>

#define S_LEN 2048
#define DIM   1024
#define NHEAD 16
#define HDIM  64
#define QSCALE 0.18033688f   // log2(e)/8, folded into Q at projection time

typedef __attribute__((ext_vector_type(8))) short bfrag;   // 8 bf16 = 4 VGPRs
typedef __attribute__((ext_vector_type(4))) float f32x4;   // MFMA C/D 16x16
typedef __attribute__((ext_vector_type(16))) float f32x16; // MFMA C/D 32x32
typedef __attribute__((ext_vector_type(4))) unsigned int u32x4;

#define MFMA(a,b,c)   __builtin_amdgcn_mfma_f32_16x16x32_bf16((a),(b),(c),0,0,0)
#define MFMA32(a,b,c) __builtin_amdgcn_mfma_f32_32x32x16_bf16((a),(b),(c),0,0,0)

__device__ __forceinline__ unsigned short f2bf(float x) {
  __hip_bfloat16 h = __float2bfloat16(x);
  return *reinterpret_cast<unsigned short*>(&h);
}

// packed 2xf32 -> 2xbf16 (v_cvt_pk_bf16_f32 on gfx950)
__device__ __forceinline__ unsigned int pk2bf(float a, float b) {
  float2 f2; f2.x = a; f2.y = b;
  __hip_bfloat162 b2 = __float22bfloat162_rn(f2);
  return *reinterpret_cast<unsigned int*>(&b2);
}

// async global->LDS, 16B per lane; LDS dest = wave-uniform base + lane*16
__device__ __forceinline__ void gll16(const unsigned short* g, unsigned short* l) {
  __builtin_amdgcn_global_load_lds(
      (const __attribute__((address_space(1))) unsigned int*)g,
      (__attribute__((address_space(3))) unsigned int*)l, 16, 0, 0);
}

// flags[0]: 0 = inputs bf16, 1 = inputs fp32
// flags[1]: mask mode 0=u8, 1=i32, 2=f32, 3=bf16
__global__ void probe(const unsigned int* __restrict__ x,
                      const unsigned int* __restrict__ mask,
                      int* __restrict__ flags) {
  const int lane = threadIdx.x;
  int insane = 0;
  for (int i = lane; i < 512; i += 64) {
    unsigned int w = x[i];
    unsigned int e = (w >> 7) & 0xFFu;
    bool sane = (e >= 90u && e <= 160u) || ((w & 0x7FFFu) == 0u);
    insane += sane ? 0 : 1;
  }
  bool all01 = true, allu8 = true, allf32 = true, allbf = true;
  for (int i = lane; i < 1024; i += 64) {
    unsigned int w = mask[i];
    all01  &= (w <= 1u);
    allu8  &= ((w & 0xFEFEFEFEu) == 0u);
    allf32 &= (w == 0u || w == 0x3F800000u);
    unsigned int lo = w & 0xFFFFu, hi = w >> 16;
    allbf  &= (lo == 0u || lo == 0x3F80u) && (hi == 0u || hi == 0x3F80u);
  }
#pragma unroll
  for (int off = 1; off < 64; off <<= 1) insane += __shfl_xor(insane, off, 64);
  const unsigned long long full = ~0ull;
  const bool g01  = __ballot(all01)  == full;
  const bool gu8  = __ballot(allu8)  == full;
  const bool gf32 = __ballot(allf32) == full;
  const bool gbf  = __ballot(allbf)  == full;
  if (lane == 0) {
    flags[0] = (insane > 128) ? 1 : 0;
    flags[1] = g01 ? 1 : (gu8 ? 0 : (gf32 ? 2 : (gbf ? 3 : 0)));
  }
}

__device__ __forceinline__ bool mask_at(const void* mk, int mode, size_t idx) {
  switch (mode) {
    case 0:  return ((const unsigned char*)mk)[idx]  != 0;
    case 1:  return ((const int*)mk)[idx]            != 0;
    case 2:  return ((const unsigned int*)mk)[idx]   != 0u;
    default: return ((const unsigned short*)mk)[idx] != 0;
  }
}

// One fused conversion kernel: x (4096 blocks) + 4 weights (512 blocks each).
__global__ __launch_bounds__(256) void cvt_all(
    const void* __restrict__ x,  const void* __restrict__ wq,
    const void* __restrict__ wk, const void* __restrict__ wv,
    const void* __restrict__ wo,
    unsigned short* __restrict__ xb,  unsigned short* __restrict__ wqb,
    unsigned short* __restrict__ wkb, unsigned short* __restrict__ wvb,
    unsigned short* __restrict__ wob, const int* __restrict__ flags) {
  const int bx = blockIdx.x;
  const void* src; unsigned short* dst; int i;
  if (bx < 4096) { src = x; dst = xb; i = bx * 256 + threadIdx.x; }
  else {
    const int r = (bx - 4096) >> 9, off = (bx - 4096) & 511;
    src = r == 0 ? wq : r == 1 ? wk : r == 2 ? wv : wo;
    dst = r == 0 ? wqb : r == 1 ? wkb : r == 2 ? wvb : wob;
    i = off * 256 + threadIdx.x;
  }
  if (flags[0]) {
    const float* p = (const float*)src + (size_t)i * 8;
    float4 a = *reinterpret_cast<const float4*>(p);
    float4 b = *reinterpret_cast<const float4*>(p + 4);
    unsigned int d0 = pk2bf(a.x, a.y), d1 = pk2bf(a.z, a.w);
    unsigned int d2 = pk2bf(b.x, b.y), d3 = pk2bf(b.z, b.w);
    uint4 o; o.x = d0; o.y = d1; o.z = d2; o.w = d3;
    *reinterpret_cast<uint4*>(dst + (size_t)i * 8) = o;
  } else {
    *reinterpret_cast<bfrag*>(dst + (size_t)i * 8) =
        reinterpret_cast<const bfrag*>(src)[i];
  }
}

// Bit-pack mask (any mode) -> u64 per 64 keys via ballot.
// TRANSPOSED layout: mb[(b*32 + word) * 2048 + q].
// grid-stride x8 (8192 blocks): cuts 16.7M-thread scheduling overhead (~-20us).
__global__ __launch_bounds__(256) void bitmask(const void* __restrict__ mk,
                                               const int* __restrict__ flags,
                                               unsigned long long* __restrict__ mb) {
  const int mode = flags[1];
  const size_t base = (size_t)blockIdx.x * 256 + threadIdx.x;
#pragma unroll
  for (int it = 0; it < 8; ++it) {
    const size_t gid = base + (size_t)it * 2097152;   // 8192*256 stride
    bool v = mask_at(mk, mode, gid);
    unsigned long long w = __ballot(v);
    if ((threadIdx.x & 63) == 0) {
      const size_t bb = gid >> 22;            // S*S = 2^22 per batch
      const size_t q  = (gid >> 11) & 2047;
      const size_t wd = (gid >> 6) & 31;
      mb[(bb * 32 + wd) * 2048 + q] = w;
    }
  }
}

// ---------------- GEMM v3: C(8192xN) = A @ Bt^T, bf16, K=1024, BK=64 ----------------
// BK=64 + XOR-swizzled staging/reads (rule 21) + bijective XCD swizzle (proven).
// cMode=3 region 2 (V) writes DIRECTLY in transposed [bh][64][s] layout.
// cMode: 1 head-split bf16, 2 plain dtype-per-flag, 3 fused-QKV head-split
// (region 0 == Q pre-scaled by QSCALE; region 2 == V transposed).
__global__ __launch_bounds__(256) void gemm128(const unsigned short* __restrict__ A,
                                               const unsigned short* __restrict__ Bt,
                                               void* __restrict__ C,
                                               const int* __restrict__ flags,
                                               int aHsplit, int cMode) {
  __shared__ unsigned short As[128 * 64];
  __shared__ unsigned short Bs[128 * 64];
  const int t = threadIdx.x, lane = t & 63, wave = t >> 6;
  const int r16 = lane & 15, quad = lane >> 4;

  // XCD-aware bijective block swizzle (both grids have nwg % 8 == 0)
  const int nwgx = gridDim.x;
  const int nwg  = nwgx * gridDim.y;
  const int orig = blockIdx.y * nwgx + blockIdx.x;
  const int cpx  = nwg >> 3;
  const int swz  = (orig & 7) * cpx + (orig >> 3);
  const int n0 = (swz % nwgx) * 128, m0 = (swz / nwgx) * 128;

  const int wm = (wave >> 1) * 64, wn = (wave & 1) * 64;
  const int srow = t >> 3;                 // 0..31 rows per staging round
  const int sgr  = (t & 7) ^ (srow & 7);   // inverse-swizzled source granule

  f32x4 acc[4][4];
#pragma unroll
  for (int i = 0; i < 4; ++i)
#pragma unroll
    for (int j = 0; j < 4; ++j) acc[i][j] = (f32x4){0.f, 0.f, 0.f, 0.f};

  for (int k0 = 0; k0 < 1024; k0 += 64) {
    __syncthreads();
#pragma unroll
    for (int rr = 0; rr < 4; ++rr) {
      const int row = rr * 32 + srow;
      const int m = m0 + row;
      const int k = k0 + sgr * 8;
      const unsigned short* ga;
      if (aHsplit) ga = A + ((size_t)(((m >> 11) << 4) + (k >> 6)) * 2048 + (m & 2047)) * 64 + (k & 63);
      else         ga = A + (size_t)m * 1024 + k;
      gll16(ga, As + rr * 2048 + wave * 512);
      const unsigned short* gb = Bt + (size_t)(n0 + row) * 1024 + k;
      gll16(gb, Bs + rr * 2048 + wave * 512);
    }
    __syncthreads();

#pragma unroll
    for (int kk = 0; kk < 2; ++kk) {
      bfrag af[4], bf[4];
#pragma unroll
      for (int i = 0; i < 4; ++i)
        af[i] = *reinterpret_cast<const bfrag*>(
            &As[(wm + i * 16 + r16) * 64 + (((kk * 4 + quad) ^ (r16 & 7)) * 8)]);
#pragma unroll
      for (int j = 0; j < 4; ++j)
        bf[j] = *reinterpret_cast<const bfrag*>(
            &Bs[(wn + j * 16 + r16) * 64 + (((kk * 4 + quad) ^ (r16 & 7)) * 8)]);
#pragma unroll
      for (int i = 0; i < 4; ++i)
#pragma unroll
        for (int j = 0; j < 4; ++j)
          acc[i][j] = MFMA(af[i], bf[j], acc[i][j]);
    }
  }

  const int oF = (cMode == 2) ? flags[0] : 0;
#pragma unroll
  for (int i = 0; i < 4; ++i)
#pragma unroll
    for (int j = 0; j < 4; ++j) {
      const int mb = m0 + wm + i * 16 + quad * 4;   // r=0 token
      const int n  = n0 + wn + j * 16 + r16;
      if (cMode == 3 && (n >> 10) == 2) {
        // V: write transposed [bh][d][s]; 4 consecutive tokens -> one 8B store
        const int nn = n & 1023;
        const int bh = (mb >> 11) * NHEAD + (nn >> 6);
        const size_t idx = (size_t)2 * 8388608 +
            ((size_t)bh * 64 + (nn & 63)) * 2048 + (mb & 2047);
        ushort4 o;
        o.x = f2bf(acc[i][j][0]); o.y = f2bf(acc[i][j][1]);
        o.z = f2bf(acc[i][j][2]); o.w = f2bf(acc[i][j][3]);
        *reinterpret_cast<ushort4*>((unsigned short*)C + idx) = o;
      } else {
#pragma unroll
        for (int r = 0; r < 4; ++r) {
          const int m = mb + r;
          const float v = acc[i][j][r];
          if (cMode == 3) {
            const int region = n >> 10, nn = n & 1023;
            const float vv = (region == 0) ? v * QSCALE : v;
            const size_t idx = (size_t)region * 8388608 +
                ((size_t)((m >> 11) * NHEAD + (nn >> 6)) * 2048 + (m & 2047)) * 64 + (nn & 63);
            ((unsigned short*)C)[idx] = f2bf(vv);
          } else if (cMode == 1) {
            const size_t idx = ((size_t)((m >> 11) * NHEAD + (n >> 6)) * 2048 + (m & 2047)) * 64 + (n & 63);
            ((unsigned short*)C)[idx] = f2bf(v);
          } else {
            const size_t idx = (size_t)m * 1024 + n;
            if (oF) ((float*)C)[idx] = v;
            else    ((unsigned short*)C)[idx] = f2bf(v);
          }
        }
      }
    }
}

// ---------------- fattn v15 == v13 (best measured, ~120us) ----------------------
// 256 threads / 4 waves, KVBLK=64, 32KB LDS, (256,3), paired QK^T (z0,z1),
// shfl P-exchange, lsum partials, mask prefetch d=1, setprio on MFMA clusters.
// v14's 2-wave variant regressed (170us: occupancy 17%, per-wave DMA doubled)
// and is reverted verbatim to the v13 body.
#if defined(__has_builtin)
#if __has_builtin(__builtin_amdgcn_permlane32_swap)
#define HAVE_PL32_SWAP 1
#endif
#endif
#ifndef HAVE_PL32_SWAP
#define HAVE_PL32_SWAP 0
#endif

__global__ __launch_bounds__(256, 3) void fattn(const unsigned short* __restrict__ qH,
                                                const unsigned short* __restrict__ kH,
                                                const unsigned short* __restrict__ vT,
                                                const unsigned long long* __restrict__ mbT,
                                                unsigned short* __restrict__ oH) {
  __shared__ unsigned short Ks[2][64 * 64];
  __shared__ unsigned short Vs[2][64 * 64];
  const int t = threadIdx.x, lane = t & 63, wave = t >> 6;
  const int l31 = lane & 31, hi = lane >> 5;
  const int bid = blockIdx.x;
  const int bh = bid & 63, qidx = bid >> 6;
  const int b = bh >> 4;
  const int qw = qidx * 128 + wave * 32;
  const size_t hbase = (size_t)bh * S_LEN;
  const int kgr = l31 & 7;  // row&7 for both K-frag and V-frag LDS reads

  // Q fragments (B-operand of QK^T): lane holds Q[qw+l31][d = 16s + 8hi + j]
  bfrag qf[4];
#pragma unroll
  for (int s = 0; s < 4; ++s)
    qf[s] = *reinterpret_cast<const bfrag*>(
        qH + (hbase + qw + l31) * 64 + s * 16 + hi * 8);

  f32x16 o0, o1;   // O[q][d] d-halves: row q = (r&3)+8*(r>>2)+4*hi, col d = l31(+32)
#pragma unroll
  for (int r = 0; r < 16; ++r) { o0[r] = 0.f; o1[r] = 0.f; }
  float ls[4] = {0.f, 0.f, 0.f, 0.f};   // 4 partials: break serial fadd chain

  const int srow = lane >> 3;
  const int sg   = (lane & 7) ^ srow;

  auto stage = [&](int buf, int kb) {
#pragma unroll
    for (int rr = 0; rr < 2; ++rr) {
      const int row = rr * 32 + wave * 8 + srow;
      gll16(kH + (hbase + kb + row) * 64 + sg * 8, &Ks[buf][rr * 2048 + wave * 512]);
      gll16(vT + ((size_t)bh * 64 + row) * 2048 + kb + sg * 8, &Vs[buf][rr * 2048 + wave * 512]);
    }
  };

  stage(0, 0);
  int cur = 0;
  // transposed mask: mbT[(b*32 + word)*2048 + q]; this lane's q-column base:
  const unsigned long long* mcol = mbT + (size_t)b * 32 * S_LEN + (qw + l31);
  unsigned long long wcur = mcol[0];   // prefetch distance 1

  // softmax + pack + in-reg transpose + PV for one 32-key c-tile
  auto smpv = [&](const f32x16& z, unsigned int wm, int c) {
#pragma unroll
    for (int s2 = 0; s2 < 2; ++s2) {
      float e[8];
#pragma unroll
      for (int j = 0; j < 8; ++j) {
        const int r = 8 * s2 + j;
        const int bitp = (r & 3) + 8 * (r >> 2);
        float ev = __builtin_amdgcn_exp2f(z[r]);
        ev = (wm & (1u << bitp)) ? ev : 0.f;
        e[j] = ev;
        ls[r & 3] += ev;
      }
      const unsigned int pwa = pk2bf(e[0], e[1]);   // keys 16s2+4hi+{0,1}
      const unsigned int pwb = pk2bf(e[2], e[3]);   // keys 16s2+4hi+{2,3}
      const unsigned int pwc = pk2bf(e[4], e[5]);   // keys 16s2+8+4hi+{0,1}
      const unsigned int pwd = pk2bf(e[6], e[7]);   // keys 16s2+8+4hi+{2,3}
      u32x4 uu;
#if HAVE_PL32_SWAP
      auto r02 = __builtin_amdgcn_permlane32_swap(pwa, pwc, false, false);
      auto r13 = __builtin_amdgcn_permlane32_swap(pwb, pwd, false, false);
      uu.x = r02[0];   // k = 8hi + {0,1}
      uu.y = r13[0];   // k = 8hi + {2,3}
      uu.z = r02[1];   // k = 8hi + {4,5}
      uu.w = r13[1];   // k = 8hi + {6,7}
#else
      const unsigned int t0 = __shfl_xor(pwa, 32, 64);
      const unsigned int t1 = __shfl_xor(pwb, 32, 64);
      const unsigned int t2 = __shfl_xor(pwc, 32, 64);
      const unsigned int t3 = __shfl_xor(pwd, 32, 64);
      uu.x = hi ? t2 : pwa;   // k = 8hi + {0,1}
      uu.y = hi ? t3 : pwb;   // k = 8hi + {2,3}
      uu.z = hi ? pwc : t0;   // k = 8hi + {4,5}
      uu.w = hi ? pwd : t1;   // k = 8hi + {6,7}
#endif
      const bfrag pf = __builtin_bit_cast(bfrag, uu);
      const int s = 2 * c + s2;  // absolute 16-key slice
      const int gv = (2 * s + hi) ^ kgr;
      bfrag v0 = *reinterpret_cast<const bfrag*>(&Vs[cur][l31 * 64 + gv * 8]);
      bfrag v1 = *reinterpret_cast<const bfrag*>(&Vs[cur][(32 + l31) * 64 + gv * 8]);
      __builtin_amdgcn_s_setprio(1);
      o0 = MFMA32(pf, v0, o0);
      o1 = MFMA32(pf, v1, o1);
      __builtin_amdgcn_s_setprio(0);
    }
  };

  for (int kb = 0; kb < S_LEN; kb += 64) {
    __syncthreads();
    const bool more = (kb + 64 < S_LEN);
    if (more) stage(cur ^ 1, kb + 64);
    const unsigned long long wnext =
        more ? mcol[(size_t)((kb >> 6) + 1) * S_LEN] : 0ull;

    // lane's keys are {32c + 4*hi + (r&3) + 8*(r>>2)}; shift by 4*hi once, then
    // bit (r&3)+8*(r>>2) of the low(c=0)/high(c=1) u32 selects.
    const unsigned int wlo = (unsigned int)(wcur >> (4 * hi));
    const unsigned int whi = (unsigned int)(wcur >> (32 + 4 * hi));

    // ---- QK^T for BOTH c-tiles first: two independent 4-chains ----
    f32x16 z0, z1;
#pragma unroll
    for (int r = 0; r < 16; ++r) { z0[r] = 0.f; z1[r] = 0.f; }
    __builtin_amdgcn_s_setprio(1);
#pragma unroll
    for (int s = 0; s < 4; ++s) {
      const int gr = (2 * s + hi) ^ kgr;
      bfrag kf0 = *reinterpret_cast<const bfrag*>(&Ks[cur][l31 * 64 + gr * 8]);
      bfrag kf1 = *reinterpret_cast<const bfrag*>(&Ks[cur][(32 + l31) * 64 + gr * 8]);
      z0 = MFMA32(kf0, qf[s], z0);
      z1 = MFMA32(kf1, qf[s], z1);
    }
    __builtin_amdgcn_s_setprio(0);

    // ---- softmax+PV c=0, then c=1 (PV(c0) MFMAs overlap softmax(c1) VALU) ----
    smpv(z0, wlo, 0);
    smpv(z1, whi, 1);

    wcur = wnext;
    cur ^= 1;
  }

  // denom: lane-local sum covers this q's keys with bit2==hi; partner has the rest
  float lsum = (ls[0] + ls[1]) + (ls[2] + ls[3]);
  lsum += __shfl_xor(lsum, 32, 64);
  const float inv = 1.f / fmaxf(lsum, 1e-30f);
#pragma unroll
  for (int r = 0; r < 16; ++r) {
    const int qr = (r & 3) + 8 * (r >> 2) + 4 * hi;
    const float sc = __shfl(inv, qr, 64);  // lane qr holds inv for q = qw+qr
    unsigned short* op = oH + (hbase + qw + qr) * 64 + l31;
    op[0]  = f2bf(o0[r] * sc);
    op[32] = f2bf(o1[r] * sc);
  }
}

// ======================= round-2 fallback (small ws) =======================
template<bool F32>
__device__ __forceinline__ bfrag load8(const void* base, size_t idx) {
  if constexpr (F32) {
    const float* p = (const float*)base + idx;
    float4 u = *reinterpret_cast<const float4*>(p);
    float4 v = *reinterpret_cast<const float4*>(p + 4);
    bfrag r;
    r[0]=(short)f2bf(u.x); r[1]=(short)f2bf(u.y); r[2]=(short)f2bf(u.z); r[3]=(short)f2bf(u.w);
    r[4]=(short)f2bf(v.x); r[5]=(short)f2bf(v.y); r[6]=(short)f2bf(v.z); r[7]=(short)f2bf(v.w);
    return r;
  } else {
    return *reinterpret_cast<const bfrag*>((const unsigned short*)base + idx);
  }
}

template<bool AF32, bool BF32>
__device__ __forceinline__ void gemm_body(const void* __restrict__ A, const void* __restrict__ Bt,
                                          void* __restrict__ C, int N, int K, bool outF32) {
  const int lane = threadIdx.x & 63, wave = threadIdx.x >> 6;
  const int r16 = lane & 15, quad = lane >> 4;
  const int m0 = (blockIdx.y * 4 + wave) * 16, n0 = blockIdx.x * 64;
  f32x4 acc[4];
#pragma unroll
  for (int i = 0; i < 4; ++i) acc[i] = (f32x4){0.f,0.f,0.f,0.f};
  const size_t aoff = (size_t)(m0 + r16) * K + quad * 8;
  const size_t boff = (size_t)(n0 + r16) * K + quad * 8;
  for (int k0 = 0; k0 < K; k0 += 32) {
    bfrag a = load8<AF32>(A, aoff + k0);
#pragma unroll
    for (int tt = 0; tt < 4; ++tt) {
      bfrag bb = load8<BF32>(Bt, boff + (size_t)tt * 16 * K + k0);
      acc[tt] = MFMA(a, bb, acc[tt]);
    }
  }
#pragma unroll
  for (int tt = 0; tt < 4; ++tt)
#pragma unroll
    for (int r = 0; r < 4; ++r) {
      const size_t ci = (size_t)(m0 + quad * 4 + r) * N + n0 + tt * 16 + r16;
      if (outF32) ((float*)C)[ci] = acc[tt][r];
      else        ((unsigned short*)C)[ci] = f2bf(acc[tt][r]);
    }
}

__global__ __launch_bounds__(256) void gemm_bt(const void* A, const void* Bt, void* C,
                                               int N, int K, const int* flags,
                                               int aFollows, int outFollows) {
  const int f = flags[0];
  const bool aF = (aFollows != 0) && (f != 0);
  const bool oF = (outFollows != 0) && (f != 0);
  if (f) { if (aF) gemm_body<true, true>(A, Bt, C, N, K, oF);
           else    gemm_body<false, true>(A, Bt, C, N, K, oF); }
  else     gemm_body<false, false>(A, Bt, C, N, K, oF);
}

__global__ __launch_bounds__(64) void fattn_r2(const unsigned short* __restrict__ xq,
                                               const unsigned short* __restrict__ xk,
                                               const unsigned short* __restrict__ xv,
                                               const void* __restrict__ mk,
                                               const int* __restrict__ flags,
                                               unsigned short* __restrict__ xo) {
  __shared__ unsigned short smemP[16 * 32];
  const int lane = threadIdx.x, r16 = lane & 15, quad = lane >> 4;
  const int q0 = blockIdx.x * 16, h = blockIdx.y, b = blockIdx.z;
  const int mmode = flags[1];
  const size_t base = (size_t)b * S_LEN * DIM + (size_t)h * HDIM;
  const size_t mbase = (size_t)b * S_LEN * S_LEN;
  bfrag aq0 = *reinterpret_cast<const bfrag*>(xq + base + (size_t)(q0 + r16) * DIM + quad * 8);
  bfrag aq1 = *reinterpret_cast<const bfrag*>(xq + base + (size_t)(q0 + r16) * DIM + 32 + quad * 8);
  f32x4 o[4];
#pragma unroll
  for (int i = 0; i < 4; ++i) o[i] = (f32x4){0.f,0.f,0.f,0.f};
  float m_r[4] = {-1e30f,-1e30f,-1e30f,-1e30f}, l_r[4] = {0.f,0.f,0.f,0.f};
  for (int kb = 0; kb < S_LEN; kb += 32) {
    const unsigned short* k0p = xk + base + (size_t)(kb + r16) * DIM + quad * 8;
    const unsigned short* k1p = k0p + (size_t)16 * DIM;
    f32x4 s0 = (f32x4){0.f,0.f,0.f,0.f}, s1 = (f32x4){0.f,0.f,0.f,0.f};
    s0 = MFMA(aq0, *reinterpret_cast<const bfrag*>(k0p), s0);
    s0 = MFMA(aq1, *reinterpret_cast<const bfrag*>(k0p + 32), s0);
    s1 = MFMA(aq0, *reinterpret_cast<const bfrag*>(k1p), s1);
    s1 = MFMA(aq1, *reinterpret_cast<const bfrag*>(k1p + 32), s1);
    float l0[4], l1[4], tmax[4];
#pragma unroll
    for (int r = 0; r < 4; ++r) {
      const size_t mrow = mbase + (size_t)(q0 + quad * 4 + r) * S_LEN + kb;
      l0[r] = mask_at(mk, mmode, mrow + r16) ? s0[r] * 0.125f : -1e30f;
      l1[r] = mask_at(mk, mmode, mrow + 16 + r16) ? s1[r] * 0.125f : -1e30f;
      tmax[r] = fmaxf(l0[r], l1[r]);
    }
#pragma unroll
    for (int off = 1; off < 16; off <<= 1)
#pragma unroll
      for (int r = 0; r < 4; ++r) tmax[r] = fmaxf(tmax[r], __shfl_xor(tmax[r], off, 64));
    float p0[4], p1[4], rsum[4];
#pragma unroll
    for (int r = 0; r < 4; ++r) {
      const float mnew = fmaxf(m_r[r], tmax[r]);
      const float alpha = __expf(m_r[r] - mnew);
      m_r[r] = mnew;
      p0[r] = (l0[r] <= -1e29f) ? 0.f : __expf(l0[r] - mnew);
      p1[r] = (l1[r] <= -1e29f) ? 0.f : __expf(l1[r] - mnew);
      rsum[r] = p0[r] + p1[r];
      l_r[r] *= alpha;
#pragma unroll
      for (int tt = 0; tt < 4; ++tt) o[tt][r] *= alpha;
    }
#pragma unroll
    for (int off = 1; off < 16; off <<= 1)
#pragma unroll
      for (int r = 0; r < 4; ++r) rsum[r] += __shfl_xor(rsum[r], off, 64);
#pragma unroll
    for (int r = 0; r < 4; ++r) l_r[r] += rsum[r];
#pragma unroll
    for (int r = 0; r < 4; ++r) {
      smemP[(quad * 4 + r) * 32 + r16] = f2bf(p0[r]);
      smemP[(quad * 4 + r) * 32 + 16 + r16] = f2bf(p1[r]);
    }
    __syncthreads();
    bfrag apf = *reinterpret_cast<const bfrag*>(&smemP[r16 * 32 + quad * 8]);
    const unsigned short* vbase = xv + base + (size_t)(kb + quad * 8) * DIM + r16;
#pragma unroll
    for (int tt = 0; tt < 4; ++tt) {
      bfrag bv;
#pragma unroll
      for (int j = 0; j < 8; ++j) bv[j] = (short)vbase[(size_t)j * DIM + tt * 16];
      o[tt] = MFMA(apf, bv, o[tt]);
    }
    __syncthreads();
  }
#pragma unroll
  for (int tt = 0; tt < 4; ++tt)
#pragma unroll
    for (int r = 0; r < 4; ++r)
      xo[base + (size_t)(q0 + quad * 4 + r) * DIM + tt * 16 + r16] = f2bf(o[tt][r] / l_r[r]);
}

extern "C" void kernel_launch(void* const* d_in, const int* in_sizes, int n_in,
                              void* d_out, int out_size, void* d_ws, size_t ws_size,
                              hipStream_t stream) {
  const void* x  = d_in[0];
  const void* mk = d_in[1];
  const void* wq = d_in[2];
  const void* wk = d_in[3];
  const void* wv = d_in[4];
  const void* wo = d_in[5];

  const size_t MiB = 1048576;
  const size_t NEED = 4096 + 90 * MiB;

  if (ws_size >= NEED) {
    char* p = (char*)d_ws;
    int* flags = (int*)p;                       p += 4096;
    unsigned short* xb  = (unsigned short*)p;   p += 16 * MiB;
    unsigned short* wqb = (unsigned short*)p;   p += 2 * MiB;
    unsigned short* wkb = (unsigned short*)p;   p += 2 * MiB;
    unsigned short* wvb = (unsigned short*)p;   p += 2 * MiB;
    unsigned short* wob = (unsigned short*)p;   p += 2 * MiB;
    unsigned long long* mb = (unsigned long long*)p; p += 2 * MiB;
    unsigned short* xqH = (unsigned short*)p;   p += 16 * MiB;  // xq/xk contiguous,
    unsigned short* xkH = (unsigned short*)p;   p += 16 * MiB;  // then V (transposed)
    unsigned short* xvT = (unsigned short*)p;   p += 16 * MiB;  // region 2 of cMode=3
    unsigned short* xoH = (unsigned short*)p;   p += 16 * MiB;  // attn out (head-split)
    (void)xkH; (void)xvT;

    probe<<<1, 64, 0, stream>>>((const unsigned int*)x, (const unsigned int*)mk, flags);
    cvt_all<<<6144, 256, 0, stream>>>(x, wq, wk, wv, wo, xb, wqb, wkb, wvb, wob, flags);
    bitmask<<<8192, 256, 0, stream>>>(mk, flags, mb);

    gemm128<<<dim3(24, 64), 256, 0, stream>>>(xb, wqb, xqH, flags, 0, 3);
    fattn<<<dim3(1024), 256, 0, stream>>>(xqH, xkH, xvT, mb, xoH);
    gemm128<<<dim3(8, 64), 256, 0, stream>>>(xoH, wob, d_out, flags, 1, 2);
  } else {
    // round-2 fallback
    int* flags = (int*)d_ws;
    unsigned short* xq = (unsigned short*)((char*)d_ws + 256);
    unsigned short* xk = xq + (size_t)8388608;
    unsigned short* xv = xk + (size_t)8388608;
    unsigned short* xo = xv + (size_t)8388608;
    probe<<<1, 64, 0, stream>>>((const unsigned int*)x, (const unsigned int*)mk, flags);
    dim3 gg(16, 128);
    gemm_bt<<<gg, 256, 0, stream>>>(x, wq, xq, 1024, 1024, flags, 1, 0);
    gemm_bt<<<gg, 256, 0, stream>>>(x, wk, xk, 1024, 1024, flags, 1, 0);
    gemm_bt<<<gg, 256, 0, stream>>>(x, wv, xv, 1024, 1024, flags, 1, 0);
    fattn_r2<<<dim3(128, NHEAD, 4), 64, 0, stream>>>(xq, xk, xv, mk, flags, xo);
    gemm_bt<<<gg, 256, 0, stream>>>(xo, wo, d_out, 1024, 1024, flags, 0, 1);
  }
}

// Round 12
// 364.246 us; speedup vs baseline: 1.1061x; 1.0407x over previous
//
#include <hip/hip_runtime.h>
#include <hip/hip_bf16.h>

#define S_LEN 2048
#define DIM   1024
#define NHEAD 16
#define HDIM  64
#define QSCALE 0.18033688f   // log2(e)/8, folded into Q at projection time

typedef __attribute__((ext_vector_type(8))) short bfrag;   // 8 bf16 = 4 VGPRs
typedef __attribute__((ext_vector_type(4))) float f32x4;   // MFMA C/D 16x16
typedef __attribute__((ext_vector_type(16))) float f32x16; // MFMA C/D 32x32
typedef __attribute__((ext_vector_type(4))) unsigned int u32x4;

#define MFMA(a,b,c)   __builtin_amdgcn_mfma_f32_16x16x32_bf16((a),(b),(c),0,0,0)
#define MFMA32(a,b,c) __builtin_amdgcn_mfma_f32_32x32x16_bf16((a),(b),(c),0,0,0)

__device__ __forceinline__ unsigned short f2bf(float x) {
  __hip_bfloat16 h = __float2bfloat16(x);
  return *reinterpret_cast<unsigned short*>(&h);
}

// packed 2xf32 -> 2xbf16 (v_cvt_pk_bf16_f32 on gfx950)
__device__ __forceinline__ unsigned int pk2bf(float a, float b) {
  float2 f2; f2.x = a; f2.y = b;
  __hip_bfloat162 b2 = __float22bfloat162_rn(f2);
  return *reinterpret_cast<unsigned int*>(&b2);
}

// async global->LDS, 16B per lane; LDS dest = wave-uniform base + lane*16
__device__ __forceinline__ void gll16(const unsigned short* g, unsigned short* l) {
  __builtin_amdgcn_global_load_lds(
      (const __attribute__((address_space(1))) unsigned int*)g,
      (__attribute__((address_space(3))) unsigned int*)l, 16, 0, 0);
}

// flags[0]: 0 = inputs bf16, 1 = inputs fp32
// flags[1]: mask mode 0=u8, 1=i32, 2=f32, 3=bf16
__global__ void probe(const unsigned int* __restrict__ x,
                      const unsigned int* __restrict__ mask,
                      int* __restrict__ flags) {
  const int lane = threadIdx.x;
  int insane = 0;
  for (int i = lane; i < 512; i += 64) {
    unsigned int w = x[i];
    unsigned int e = (w >> 7) & 0xFFu;
    bool sane = (e >= 90u && e <= 160u) || ((w & 0x7FFFu) == 0u);
    insane += sane ? 0 : 1;
  }
  bool all01 = true, allu8 = true, allf32 = true, allbf = true;
  for (int i = lane; i < 1024; i += 64) {
    unsigned int w = mask[i];
    all01  &= (w <= 1u);
    allu8  &= ((w & 0xFEFEFEFEu) == 0u);
    allf32 &= (w == 0u || w == 0x3F800000u);
    unsigned int lo = w & 0xFFFFu, hi = w >> 16;
    allbf  &= (lo == 0u || lo == 0x3F80u) && (hi == 0u || hi == 0x3F80u);
  }
#pragma unroll
  for (int off = 1; off < 64; off <<= 1) insane += __shfl_xor(insane, off, 64);
  const unsigned long long full = ~0ull;
  const bool g01  = __ballot(all01)  == full;
  const bool gu8  = __ballot(allu8)  == full;
  const bool gf32 = __ballot(allf32) == full;
  const bool gbf  = __ballot(allbf)  == full;
  if (lane == 0) {
    flags[0] = (insane > 128) ? 1 : 0;
    flags[1] = g01 ? 1 : (gu8 ? 0 : (gf32 ? 2 : (gbf ? 3 : 0)));
  }
}

__device__ __forceinline__ bool mask_at(const void* mk, int mode, size_t idx) {
  switch (mode) {
    case 0:  return ((const unsigned char*)mk)[idx]  != 0;
    case 1:  return ((const int*)mk)[idx]            != 0;
    case 2:  return ((const unsigned int*)mk)[idx]   != 0u;
    default: return ((const unsigned short*)mk)[idx] != 0;
  }
}

// One fused conversion kernel: x (4096 blocks) + 4 weights (512 blocks each).
__global__ __launch_bounds__(256) void cvt_all(
    const void* __restrict__ x,  const void* __restrict__ wq,
    const void* __restrict__ wk, const void* __restrict__ wv,
    const void* __restrict__ wo,
    unsigned short* __restrict__ xb,  unsigned short* __restrict__ wqb,
    unsigned short* __restrict__ wkb, unsigned short* __restrict__ wvb,
    unsigned short* __restrict__ wob, const int* __restrict__ flags) {
  const int bx = blockIdx.x;
  const void* src; unsigned short* dst; int i;
  if (bx < 4096) { src = x; dst = xb; i = bx * 256 + threadIdx.x; }
  else {
    const int r = (bx - 4096) >> 9, off = (bx - 4096) & 511;
    src = r == 0 ? wq : r == 1 ? wk : r == 2 ? wv : wo;
    dst = r == 0 ? wqb : r == 1 ? wkb : r == 2 ? wvb : wob;
    i = off * 256 + threadIdx.x;
  }
  if (flags[0]) {
    const float* p = (const float*)src + (size_t)i * 8;
    float4 a = *reinterpret_cast<const float4*>(p);
    float4 b = *reinterpret_cast<const float4*>(p + 4);
    unsigned int d0 = pk2bf(a.x, a.y), d1 = pk2bf(a.z, a.w);
    unsigned int d2 = pk2bf(b.x, b.y), d3 = pk2bf(b.z, b.w);
    uint4 o; o.x = d0; o.y = d1; o.z = d2; o.w = d3;
    *reinterpret_cast<uint4*>(dst + (size_t)i * 8) = o;
  } else {
    *reinterpret_cast<bfrag*>(dst + (size_t)i * 8) =
        reinterpret_cast<const bfrag*>(src)[i];
  }
}

// Bit-pack mask (any mode) -> u64 per 64 keys via ballot.
// TRANSPOSED layout: mb[(b*32 + word) * 2048 + q].
// grid-stride x8 (8192 blocks).
__global__ __launch_bounds__(256) void bitmask(const void* __restrict__ mk,
                                               const int* __restrict__ flags,
                                               unsigned long long* __restrict__ mb) {
  const int mode = flags[1];
  const size_t base = (size_t)blockIdx.x * 256 + threadIdx.x;
#pragma unroll
  for (int it = 0; it < 8; ++it) {
    const size_t gid = base + (size_t)it * 2097152;   // 8192*256 stride
    bool v = mask_at(mk, mode, gid);
    unsigned long long w = __ballot(v);
    if ((threadIdx.x & 63) == 0) {
      const size_t bb = gid >> 22;            // S*S = 2^22 per batch
      const size_t q  = (gid >> 11) & 2047;
      const size_t wd = (gid >> 6) & 31;
      mb[(bb * 32 + wd) * 2048 + q] = w;
    }
  }
}

// ---------------- GEMM v3: C(8192xN) = A @ Bt^T, bf16, K=1024, BK=64 ----------------
// BK=64 + XOR-swizzled staging/reads (rule 21) + bijective XCD swizzle (proven).
// cMode=3 region 2 (V) writes DIRECTLY in transposed [bh][64][s] layout.
// cMode: 1 head-split bf16, 2 plain dtype-per-flag, 3 fused-QKV head-split
// (region 0 == Q pre-scaled by QSCALE; region 2 == V transposed).
__global__ __launch_bounds__(256) void gemm128(const unsigned short* __restrict__ A,
                                               const unsigned short* __restrict__ Bt,
                                               void* __restrict__ C,
                                               const int* __restrict__ flags,
                                               int aHsplit, int cMode) {
  __shared__ unsigned short As[128 * 64];
  __shared__ unsigned short Bs[128 * 64];
  const int t = threadIdx.x, lane = t & 63, wave = t >> 6;
  const int r16 = lane & 15, quad = lane >> 4;

  // XCD-aware bijective block swizzle (both grids have nwg % 8 == 0)
  const int nwgx = gridDim.x;
  const int nwg  = nwgx * gridDim.y;
  const int orig = blockIdx.y * nwgx + blockIdx.x;
  const int cpx  = nwg >> 3;
  const int swz  = (orig & 7) * cpx + (orig >> 3);
  const int n0 = (swz % nwgx) * 128, m0 = (swz / nwgx) * 128;

  const int wm = (wave >> 1) * 64, wn = (wave & 1) * 64;
  const int srow = t >> 3;                 // 0..31 rows per staging round
  const int sgr  = (t & 7) ^ (srow & 7);   // inverse-swizzled source granule

  f32x4 acc[4][4];
#pragma unroll
  for (int i = 0; i < 4; ++i)
#pragma unroll
    for (int j = 0; j < 4; ++j) acc[i][j] = (f32x4){0.f, 0.f, 0.f, 0.f};

  for (int k0 = 0; k0 < 1024; k0 += 64) {
    __syncthreads();
#pragma unroll
    for (int rr = 0; rr < 4; ++rr) {
      const int row = rr * 32 + srow;
      const int m = m0 + row;
      const int k = k0 + sgr * 8;
      const unsigned short* ga;
      if (aHsplit) ga = A + ((size_t)(((m >> 11) << 4) + (k >> 6)) * 2048 + (m & 2047)) * 64 + (k & 63);
      else         ga = A + (size_t)m * 1024 + k;
      gll16(ga, As + rr * 2048 + wave * 512);
      const unsigned short* gb = Bt + (size_t)(n0 + row) * 1024 + k;
      gll16(gb, Bs + rr * 2048 + wave * 512);
    }
    __syncthreads();

#pragma unroll
    for (int kk = 0; kk < 2; ++kk) {
      bfrag af[4], bf[4];
#pragma unroll
      for (int i = 0; i < 4; ++i)
        af[i] = *reinterpret_cast<const bfrag*>(
            &As[(wm + i * 16 + r16) * 64 + (((kk * 4 + quad) ^ (r16 & 7)) * 8)]);
#pragma unroll
      for (int j = 0; j < 4; ++j)
        bf[j] = *reinterpret_cast<const bfrag*>(
            &Bs[(wn + j * 16 + r16) * 64 + (((kk * 4 + quad) ^ (r16 & 7)) * 8)]);
#pragma unroll
      for (int i = 0; i < 4; ++i)
#pragma unroll
        for (int j = 0; j < 4; ++j)
          acc[i][j] = MFMA(af[i], bf[j], acc[i][j]);
    }
  }

  const int oF = (cMode == 2) ? flags[0] : 0;
#pragma unroll
  for (int i = 0; i < 4; ++i)
#pragma unroll
    for (int j = 0; j < 4; ++j) {
      const int mb = m0 + wm + i * 16 + quad * 4;   // r=0 token
      const int n  = n0 + wn + j * 16 + r16;
      if (cMode == 3 && (n >> 10) == 2) {
        // V: write transposed [bh][d][s]; 4 consecutive tokens -> one 8B store
        const int nn = n & 1023;
        const int bh = (mb >> 11) * NHEAD + (nn >> 6);
        const size_t idx = (size_t)2 * 8388608 +
            ((size_t)bh * 64 + (nn & 63)) * 2048 + (mb & 2047);
        ushort4 o;
        o.x = f2bf(acc[i][j][0]); o.y = f2bf(acc[i][j][1]);
        o.z = f2bf(acc[i][j][2]); o.w = f2bf(acc[i][j][3]);
        *reinterpret_cast<ushort4*>((unsigned short*)C + idx) = o;
      } else {
#pragma unroll
        for (int r = 0; r < 4; ++r) {
          const int m = mb + r;
          const float v = acc[i][j][r];
          if (cMode == 3) {
            const int region = n >> 10, nn = n & 1023;
            const float vv = (region == 0) ? v * QSCALE : v;
            const size_t idx = (size_t)region * 8388608 +
                ((size_t)((m >> 11) * NHEAD + (nn >> 6)) * 2048 + (m & 2047)) * 64 + (nn & 63);
            ((unsigned short*)C)[idx] = f2bf(vv);
          } else if (cMode == 1) {
            const size_t idx = ((size_t)((m >> 11) * NHEAD + (n >> 6)) * 2048 + (m & 2047)) * 64 + (n & 63);
            ((unsigned short*)C)[idx] = f2bf(v);
          } else {
            const size_t idx = (size_t)m * 1024 + n;
            if (oF) ((float*)C)[idx] = v;
            else    ((unsigned short*)C)[idx] = f2bf(v);
          }
        }
      }
    }
}

// ---------------- fattn v16: v15 + MFMA-computed softmax denominator ------------
// v15 structure kept (256 thr, KVBLK=64, (256,3), paired QK^T, shfl exchange,
// mask prefetch d=1). NEW: lsum computed as lacc = MFMA32(pf, ones, lacc) --
// B=all-ones makes Sum_k P[q][k] land in lacc with the SAME row layout as o0/o1,
// deleting 64 VALU fadds/iter AND the entire epilogue shuffle tree (2 shfl_xor
// + 16 shfl). Numerator/denominator now both use bf16-quantized P (consistent).
// Spill tripwire: WRITE_SIZE must stay ~16MB.
#if defined(__has_builtin)
#if __has_builtin(__builtin_amdgcn_permlane32_swap)
#define HAVE_PL32_SWAP 1
#endif
#endif
#ifndef HAVE_PL32_SWAP
#define HAVE_PL32_SWAP 0
#endif

__global__ __launch_bounds__(256, 3) void fattn(const unsigned short* __restrict__ qH,
                                                const unsigned short* __restrict__ kH,
                                                const unsigned short* __restrict__ vT,
                                                const unsigned long long* __restrict__ mbT,
                                                unsigned short* __restrict__ oH) {
  __shared__ unsigned short Ks[2][64 * 64];
  __shared__ unsigned short Vs[2][64 * 64];
  const int t = threadIdx.x, lane = t & 63, wave = t >> 6;
  const int l31 = lane & 31, hi = lane >> 5;
  const int bid = blockIdx.x;
  const int bh = bid & 63, qidx = bid >> 6;
  const int b = bh >> 4;
  const int qw = qidx * 128 + wave * 32;
  const size_t hbase = (size_t)bh * S_LEN;
  const int kgr = l31 & 7;  // row&7 for both K-frag and V-frag LDS reads

  // Q fragments (B-operand of QK^T): lane holds Q[qw+l31][d = 16s + 8hi + j]
  bfrag qf[4];
#pragma unroll
  for (int s = 0; s < 4; ++s)
    qf[s] = *reinterpret_cast<const bfrag*>(
        qH + (hbase + qw + l31) * 64 + s * 16 + hi * 8);

  // all-ones bf16 B-operand (layout-independent: every element is 1.0)
  u32x4 uo; uo.x = 0x3F803F80u; uo.y = 0x3F803F80u; uo.z = 0x3F803F80u; uo.w = 0x3F803F80u;
  const bfrag onef = __builtin_bit_cast(bfrag, uo);

  f32x16 o0, o1;   // O[q][d] d-halves: row q = (r&3)+8*(r>>2)+4*hi, col d = l31(+32)
  f32x16 lacc;     // denominator: same row layout, every column = row-sum of P
#pragma unroll
  for (int r = 0; r < 16; ++r) { o0[r] = 0.f; o1[r] = 0.f; lacc[r] = 0.f; }

  const int srow = lane >> 3;
  const int sg   = (lane & 7) ^ srow;

  auto stage = [&](int buf, int kb) {
#pragma unroll
    for (int rr = 0; rr < 2; ++rr) {
      const int row = rr * 32 + wave * 8 + srow;
      gll16(kH + (hbase + kb + row) * 64 + sg * 8, &Ks[buf][rr * 2048 + wave * 512]);
      gll16(vT + ((size_t)bh * 64 + row) * 2048 + kb + sg * 8, &Vs[buf][rr * 2048 + wave * 512]);
    }
  };

  stage(0, 0);
  int cur = 0;
  // transposed mask: mbT[(b*32 + word)*2048 + q]; this lane's q-column base:
  const unsigned long long* mcol = mbT + (size_t)b * 32 * S_LEN + (qw + l31);
  unsigned long long wcur = mcol[0];   // prefetch distance 1

  // softmax + pack + in-reg transpose + PV (+denominator MFMA) for one c-tile
  auto smpv = [&](const f32x16& z, unsigned int wm, int c) {
#pragma unroll
    for (int s2 = 0; s2 < 2; ++s2) {
      float e[8];
#pragma unroll
      for (int j = 0; j < 8; ++j) {
        const int r = 8 * s2 + j;
        const int bitp = (r & 3) + 8 * (r >> 2);
        float ev = __builtin_amdgcn_exp2f(z[r]);
        ev = (wm & (1u << bitp)) ? ev : 0.f;
        e[j] = ev;
      }
      const unsigned int pwa = pk2bf(e[0], e[1]);   // keys 16s2+4hi+{0,1}
      const unsigned int pwb = pk2bf(e[2], e[3]);   // keys 16s2+4hi+{2,3}
      const unsigned int pwc = pk2bf(e[4], e[5]);   // keys 16s2+8+4hi+{0,1}
      const unsigned int pwd = pk2bf(e[6], e[7]);   // keys 16s2+8+4hi+{2,3}
      u32x4 uu;
#if HAVE_PL32_SWAP
      auto r02 = __builtin_amdgcn_permlane32_swap(pwa, pwc, false, false);
      auto r13 = __builtin_amdgcn_permlane32_swap(pwb, pwd, false, false);
      uu.x = r02[0];   // k = 8hi + {0,1}
      uu.y = r13[0];   // k = 8hi + {2,3}
      uu.z = r02[1];   // k = 8hi + {4,5}
      uu.w = r13[1];   // k = 8hi + {6,7}
#else
      const unsigned int t0 = __shfl_xor(pwa, 32, 64);
      const unsigned int t1 = __shfl_xor(pwb, 32, 64);
      const unsigned int t2 = __shfl_xor(pwc, 32, 64);
      const unsigned int t3 = __shfl_xor(pwd, 32, 64);
      uu.x = hi ? t2 : pwa;   // k = 8hi + {0,1}
      uu.y = hi ? t3 : pwb;   // k = 8hi + {2,3}
      uu.z = hi ? pwc : t0;   // k = 8hi + {4,5}
      uu.w = hi ? pwd : t1;   // k = 8hi + {6,7}
#endif
      const bfrag pf = __builtin_bit_cast(bfrag, uu);
      const int s = 2 * c + s2;  // absolute 16-key slice
      const int gv = (2 * s + hi) ^ kgr;
      bfrag v0 = *reinterpret_cast<const bfrag*>(&Vs[cur][l31 * 64 + gv * 8]);
      bfrag v1 = *reinterpret_cast<const bfrag*>(&Vs[cur][(32 + l31) * 64 + gv * 8]);
      __builtin_amdgcn_s_setprio(1);
      o0 = MFMA32(pf, v0, o0);
      o1 = MFMA32(pf, v1, o1);
      lacc = MFMA32(pf, onef, lacc);   // denominator on the MFMA pipe
      __builtin_amdgcn_s_setprio(0);
    }
  };

  for (int kb = 0; kb < S_LEN; kb += 64) {
    __syncthreads();
    const bool more = (kb + 64 < S_LEN);
    if (more) stage(cur ^ 1, kb + 64);
    const unsigned long long wnext =
        more ? mcol[(size_t)((kb >> 6) + 1) * S_LEN] : 0ull;

    // lane's keys are {32c + 4*hi + (r&3) + 8*(r>>2)}; shift by 4*hi once, then
    // bit (r&3)+8*(r>>2) of the low(c=0)/high(c=1) u32 selects.
    const unsigned int wlo = (unsigned int)(wcur >> (4 * hi));
    const unsigned int whi = (unsigned int)(wcur >> (32 + 4 * hi));

    // ---- QK^T for BOTH c-tiles first: two independent 4-chains ----
    f32x16 z0, z1;
#pragma unroll
    for (int r = 0; r < 16; ++r) { z0[r] = 0.f; z1[r] = 0.f; }
    __builtin_amdgcn_s_setprio(1);
#pragma unroll
    for (int s = 0; s < 4; ++s) {
      const int gr = (2 * s + hi) ^ kgr;
      bfrag kf0 = *reinterpret_cast<const bfrag*>(&Ks[cur][l31 * 64 + gr * 8]);
      bfrag kf1 = *reinterpret_cast<const bfrag*>(&Ks[cur][(32 + l31) * 64 + gr * 8]);
      z0 = MFMA32(kf0, qf[s], z0);
      z1 = MFMA32(kf1, qf[s], z1);
    }
    __builtin_amdgcn_s_setprio(0);

    // ---- softmax+PV c=0, then c=1 (PV(c0) MFMAs overlap softmax(c1) VALU) ----
    smpv(z0, wlo, 0);
    smpv(z1, whi, 1);

    wcur = wnext;
    cur ^= 1;
  }

  // epilogue: lacc rows align with o0/o1 rows -> no shuffles at all
#pragma unroll
  for (int r = 0; r < 16; ++r) {
    const int qr = (r & 3) + 8 * (r >> 2) + 4 * hi;
    const float sc = 1.f / fmaxf(lacc[r], 1e-30f);
    unsigned short* op = oH + (hbase + qw + qr) * 64 + l31;
    op[0]  = f2bf(o0[r] * sc);
    op[32] = f2bf(o1[r] * sc);
  }
}

// ======================= round-2 fallback (small ws) =======================
template<bool F32>
__device__ __forceinline__ bfrag load8(const void* base, size_t idx) {
  if constexpr (F32) {
    const float* p = (const float*)base + idx;
    float4 u = *reinterpret_cast<const float4*>(p);
    float4 v = *reinterpret_cast<const float4*>(p + 4);
    bfrag r;
    r[0]=(short)f2bf(u.x); r[1]=(short)f2bf(u.y); r[2]=(short)f2bf(u.z); r[3]=(short)f2bf(u.w);
    r[4]=(short)f2bf(v.x); r[5]=(short)f2bf(v.y); r[6]=(short)f2bf(v.z); r[7]=(short)f2bf(v.w);
    return r;
  } else {
    return *reinterpret_cast<const bfrag*>((const unsigned short*)base + idx);
  }
}

template<bool AF32, bool BF32>
__device__ __forceinline__ void gemm_body(const void* __restrict__ A, const void* __restrict__ Bt,
                                          void* __restrict__ C, int N, int K, bool outF32) {
  const int lane = threadIdx.x & 63, wave = threadIdx.x >> 6;
  const int r16 = lane & 15, quad = lane >> 4;
  const int m0 = (blockIdx.y * 4 + wave) * 16, n0 = blockIdx.x * 64;
  f32x4 acc[4];
#pragma unroll
  for (int i = 0; i < 4; ++i) acc[i] = (f32x4){0.f,0.f,0.f,0.f};
  const size_t aoff = (size_t)(m0 + r16) * K + quad * 8;
  const size_t boff = (size_t)(n0 + r16) * K + quad * 8;
  for (int k0 = 0; k0 < K; k0 += 32) {
    bfrag a = load8<AF32>(A, aoff + k0);
#pragma unroll
    for (int tt = 0; tt < 4; ++tt) {
      bfrag bb = load8<BF32>(Bt, boff + (size_t)tt * 16 * K + k0);
      acc[tt] = MFMA(a, bb, acc[tt]);
    }
  }
#pragma unroll
  for (int tt = 0; tt < 4; ++tt)
#pragma unroll
    for (int r = 0; r < 4; ++r) {
      const size_t ci = (size_t)(m0 + quad * 4 + r) * N + n0 + tt * 16 + r16;
      if (outF32) ((float*)C)[ci] = acc[tt][r];
      else        ((unsigned short*)C)[ci] = f2bf(acc[tt][r]);
    }
}

__global__ __launch_bounds__(256) void gemm_bt(const void* A, const void* Bt, void* C,
                                               int N, int K, const int* flags,
                                               int aFollows, int outFollows) {
  const int f = flags[0];
  const bool aF = (aFollows != 0) && (f != 0);
  const bool oF = (outFollows != 0) && (f != 0);
  if (f) { if (aF) gemm_body<true, true>(A, Bt, C, N, K, oF);
           else    gemm_body<false, true>(A, Bt, C, N, K, oF); }
  else     gemm_body<false, false>(A, Bt, C, N, K, oF);
}

__global__ __launch_bounds__(64) void fattn_r2(const unsigned short* __restrict__ xq,
                                               const unsigned short* __restrict__ xk,
                                               const unsigned short* __restrict__ xv,
                                               const void* __restrict__ mk,
                                               const int* __restrict__ flags,
                                               unsigned short* __restrict__ xo) {
  __shared__ unsigned short smemP[16 * 32];
  const int lane = threadIdx.x, r16 = lane & 15, quad = lane >> 4;
  const int q0 = blockIdx.x * 16, h = blockIdx.y, b = blockIdx.z;
  const int mmode = flags[1];
  const size_t base = (size_t)b * S_LEN * DIM + (size_t)h * HDIM;
  const size_t mbase = (size_t)b * S_LEN * S_LEN;
  bfrag aq0 = *reinterpret_cast<const bfrag*>(xq + base + (size_t)(q0 + r16) * DIM + quad * 8);
  bfrag aq1 = *reinterpret_cast<const bfrag*>(xq + base + (size_t)(q0 + r16) * DIM + 32 + quad * 8);
  f32x4 o[4];
#pragma unroll
  for (int i = 0; i < 4; ++i) o[i] = (f32x4){0.f,0.f,0.f,0.f};
  float m_r[4] = {-1e30f,-1e30f,-1e30f,-1e30f}, l_r[4] = {0.f,0.f,0.f,0.f};
  for (int kb = 0; kb < S_LEN; kb += 32) {
    const unsigned short* k0p = xk + base + (size_t)(kb + r16) * DIM + quad * 8;
    const unsigned short* k1p = k0p + (size_t)16 * DIM;
    f32x4 s0 = (f32x4){0.f,0.f,0.f,0.f}, s1 = (f32x4){0.f,0.f,0.f,0.f};
    s0 = MFMA(aq0, *reinterpret_cast<const bfrag*>(k0p), s0);
    s0 = MFMA(aq1, *reinterpret_cast<const bfrag*>(k0p + 32), s0);
    s1 = MFMA(aq0, *reinterpret_cast<const bfrag*>(k1p), s1);
    s1 = MFMA(aq1, *reinterpret_cast<const bfrag*>(k1p + 32), s1);
    float l0[4], l1[4], tmax[4];
#pragma unroll
    for (int r = 0; r < 4; ++r) {
      const size_t mrow = mbase + (size_t)(q0 + quad * 4 + r) * S_LEN + kb;
      l0[r] = mask_at(mk, mmode, mrow + r16) ? s0[r] * 0.125f : -1e30f;
      l1[r] = mask_at(mk, mmode, mrow + 16 + r16) ? s1[r] * 0.125f : -1e30f;
      tmax[r] = fmaxf(l0[r], l1[r]);
    }
#pragma unroll
    for (int off = 1; off < 16; off <<= 1)
#pragma unroll
      for (int r = 0; r < 4; ++r) tmax[r] = fmaxf(tmax[r], __shfl_xor(tmax[r], off, 64));
    float p0[4], p1[4], rsum[4];
#pragma unroll
    for (int r = 0; r < 4; ++r) {
      const float mnew = fmaxf(m_r[r], tmax[r]);
      const float alpha = __expf(m_r[r] - mnew);
      m_r[r] = mnew;
      p0[r] = (l0[r] <= -1e29f) ? 0.f : __expf(l0[r] - mnew);
      p1[r] = (l1[r] <= -1e29f) ? 0.f : __expf(l1[r] - mnew);
      rsum[r] = p0[r] + p1[r];
      l_r[r] *= alpha;
#pragma unroll
      for (int tt = 0; tt < 4; ++tt) o[tt][r] *= alpha;
    }
#pragma unroll
    for (int off = 1; off < 16; off <<= 1)
#pragma unroll
      for (int r = 0; r < 4; ++r) rsum[r] += __shfl_xor(rsum[r], off, 64);
#pragma unroll
    for (int r = 0; r < 4; ++r) l_r[r] += rsum[r];
#pragma unroll
    for (int r = 0; r < 4; ++r) {
      smemP[(quad * 4 + r) * 32 + r16] = f2bf(p0[r]);
      smemP[(quad * 4 + r) * 32 + 16 + r16] = f2bf(p1[r]);
    }
    __syncthreads();
    bfrag apf = *reinterpret_cast<const bfrag*>(&smemP[r16 * 32 + quad * 8]);
    const unsigned short* vbase = xv + base + (size_t)(kb + quad * 8) * DIM + r16;
#pragma unroll
    for (int tt = 0; tt < 4; ++tt) {
      bfrag bv;
#pragma unroll
      for (int j = 0; j < 8; ++j) bv[j] = (short)vbase[(size_t)j * DIM + tt * 16];
      o[tt] = MFMA(apf, bv, o[tt]);
    }
    __syncthreads();
  }
#pragma unroll
  for (int tt = 0; tt < 4; ++tt)
#pragma unroll
    for (int r = 0; r < 4; ++r)
      xo[base + (size_t)(q0 + quad * 4 + r) * DIM + tt * 16 + r16] = f2bf(o[tt][r] / l_r[r]);
}

extern "C" void kernel_launch(void* const* d_in, const int* in_sizes, int n_in,
                              void* d_out, int out_size, void* d_ws, size_t ws_size,
                              hipStream_t stream) {
  const void* x  = d_in[0];
  const void* mk = d_in[1];
  const void* wq = d_in[2];
  const void* wk = d_in[3];
  const void* wv = d_in[4];
  const void* wo = d_in[5];

  const size_t MiB = 1048576;
  const size_t NEED = 4096 + 90 * MiB;

  if (ws_size >= NEED) {
    char* p = (char*)d_ws;
    int* flags = (int*)p;                       p += 4096;
    unsigned short* xb  = (unsigned short*)p;   p += 16 * MiB;
    unsigned short* wqb = (unsigned short*)p;   p += 2 * MiB;
    unsigned short* wkb = (unsigned short*)p;   p += 2 * MiB;
    unsigned short* wvb = (unsigned short*)p;   p += 2 * MiB;
    unsigned short* wob = (unsigned short*)p;   p += 2 * MiB;
    unsigned long long* mb = (unsigned long long*)p; p += 2 * MiB;
    unsigned short* xqH = (unsigned short*)p;   p += 16 * MiB;  // xq/xk contiguous,
    unsigned short* xkH = (unsigned short*)p;   p += 16 * MiB;  // then V (transposed)
    unsigned short* xvT = (unsigned short*)p;   p += 16 * MiB;  // region 2 of cMode=3
    unsigned short* xoH = (unsigned short*)p;   p += 16 * MiB;  // attn out (head-split)
    (void)xkH; (void)xvT;

    probe<<<1, 64, 0, stream>>>((const unsigned int*)x, (const unsigned int*)mk, flags);
    cvt_all<<<6144, 256, 0, stream>>>(x, wq, wk, wv, wo, xb, wqb, wkb, wvb, wob, flags);
    bitmask<<<8192, 256, 0, stream>>>(mk, flags, mb);

    gemm128<<<dim3(24, 64), 256, 0, stream>>>(xb, wqb, xqH, flags, 0, 3);
    fattn<<<dim3(1024), 256, 0, stream>>>(xqH, xkH, xvT, mb, xoH);
    gemm128<<<dim3(8, 64), 256, 0, stream>>>(xoH, wob, d_out, flags, 1, 2);
  } else {
    // round-2 fallback
    int* flags = (int*)d_ws;
    unsigned short* xq = (unsigned short*)((char*)d_ws + 256);
    unsigned short* xk = xq + (size_t)8388608;
    unsigned short* xv = xk + (size_t)8388608;
    unsigned short* xo = xv + (size_t)8388608;
    probe<<<1, 64, 0, stream>>>((const unsigned int*)x, (const unsigned int*)mk, flags);
    dim3 gg(16, 128);
    gemm_bt<<<gg, 256, 0, stream>>>(x, wq, xq, 1024, 1024, flags, 1, 0);
    gemm_bt<<<gg, 256, 0, stream>>>(x, wk, xk, 1024, 1024, flags, 1, 0);
    gemm_bt<<<gg, 256, 0, stream>>>(x, wv, xv, 1024, 1024, flags, 1, 0);
    fattn_r2<<<dim3(128, NHEAD, 4), 64, 0, stream>>>(xq, xk, xv, mk, flags, xo);
    gemm_bt<<<gg, 256, 0, stream>>>(xo, wo, d_out, 1024, 1024, flags, 0, 1);
  }
}